// Round 3
// baseline (417.339 us; speedup 1.0000x reference)
//
#include <hip/hip_runtime.h>
#include <math.h>

#define NEGV 1000000000000.0f
#define LDSTR 68   // 64 + 4 pad: keeps 16B alignment for float4 LDS reads, breaks bank conflicts

typedef float nt_float4 __attribute__((ext_vector_type(4)));  // clang-native for nontemporal builtin

// ---------------- Kernel 1: h = x@W1+b1; RoPE -> qw,kw; bias = (h@W2+b2)/2 ----------------
// grid 256 blocks x 256 threads; each block handles 16 rows of the 4096 (b*s) rows.
__global__ __launch_bounds__(256) void k1_fused(
    const float* __restrict__ x,    // (4096, 768)
    const float* __restrict__ W1,   // (768, 128)
    const float* __restrict__ b1,   // (128)
    const float* __restrict__ W2,   // (128, 32)
    const float* __restrict__ b2,   // (32)
    float* __restrict__ qw,         // (4096, 64)
    float* __restrict__ kw,         // (4096, 64)
    float* __restrict__ bias)       // (4, 32, 1024)
{
    __shared__ float hs[16][128];
    const int t    = threadIdx.x;
    const int row0 = blockIdx.x * 16;
    const int j    = t & 127;
    // rh is wave-uniform (waves 0,1 -> 0; waves 2,3 -> 1). readfirstlane makes the
    // uniformity provable so x loads become s_load_dwordxN (scalar path, frees VMEM).
    const int rh = __builtin_amdgcn_readfirstlane((int)threadIdx.x) >> 7;

    float acc[8] = {0.f,0.f,0.f,0.f,0.f,0.f,0.f,0.f};
    #pragma unroll 4
    for (int k = 0; k < 768; ++k) {
        const float w = W1[k * 128 + j];          // coalesced vector load, L1/L2-resident
        #pragma unroll
        for (int r = 0; r < 8; ++r)
            acc[r] = fmaf(x[(size_t)(row0 + 2*r + rh) * 768 + k], w, acc[r]);
    }
    const float bj = b1[j];
    #pragma unroll
    for (int r = 0; r < 8; ++r) hs[2*r + rh][j] = acc[r] + bj;
    __syncthreads();

    // RoPE. qw[c]=h[2c], kw[c]=h[2c+1]
    for (int idx = t; idx < 16 * 64; idx += 256) {
        const int r = idx >> 6, c = idx & 63;
        const int rowg = row0 + r;
        const int s = rowg & 1023;
        const int f = c & 31;
        const float invf = exp2f(-0.4152410118609203f * (float)f); // 10000^(-f/32)
        const float ang = (float)s * invf;
        float sn, cs;
        sincosf(ang, &sn, &cs);
        const int   pc  = (c & 1) ? (c - 1) : (c + 1);
        const float sgn = (c & 1) ? sn : -sn;
        const float qv = fmaf(hs[r][2*c],     cs, hs[r][2*pc]     * sgn);
        const float kv = fmaf(hs[r][2*c + 1], cs, hs[r][2*pc + 1] * sgn);
        qw[(size_t)rowg * 64 + c] = qv;
        kw[(size_t)rowg * 64 + c] = kv;
    }

    // bias[b][c][s] = (h[row] . W2[:,c] + b2[c]) * 0.5
    for (int idx = t; idx < 16 * 32; idx += 256) {
        const int r = idx >> 5, c = idx & 31;
        const int rowg = row0 + r;
        const int s = rowg & 1023, bb = rowg >> 10;
        float a = 0.f;
        #pragma unroll 4
        for (int k = 0; k < 128; ++k)
            a = fmaf(hs[r][k], W2[k * 32 + c], a);
        bias[(size_t)(bb * 32 + c) * 1024 + s] = (a + b2[c]) * 0.5f;
    }
}

// ---------------- Kernel 2: out[b,o,m,n] = qk/8 + bA[o][n] + bB[o][m], mask + causal ------
// grid (16,16,4) = (nTile, mTile, b); 256 threads; 64x64 (m,n) tile; 4x4 per thread.
__global__ __launch_bounds__(256) void k2_outer(
    const float* __restrict__ qw, const float* __restrict__ kw,
    const float* __restrict__ bias, const float* __restrict__ mask,
    float* __restrict__ out)
{
    __shared__ float qs[64 * LDSTR];   // [k][m]
    __shared__ float ks[64 * LDSTR];   // [k][n]
    __shared__ float bA[16][64];       // bias[b][2o][n-tile]
    __shared__ float bB[16][64];       // bias[b][2o+1][m-tile]
    __shared__ float padv[64];

    const int t  = threadIdx.x;
    const int n0 = blockIdx.x * 64;
    const int m0 = blockIdx.y * 64;
    const int b  = blockIdx.z;

    // Stage q/k tiles transposed into LDS ([k][m] layout so compute reads are b128 broadcast)
    const float4* qg = (const float4*)(qw + (size_t)(b * 1024 + m0) * 64);
    const float4* kg = (const float4*)(kw + (size_t)(b * 1024 + n0) * 64);
    #pragma unroll
    for (int it = 0; it < 4; ++it) {
        const int idx = t + it * 256;          // 0..1023 ; = m*16 + kgp
        const int m = idx >> 4, kgp = idx & 15;
        float4 v = qg[idx];
        qs[(4*kgp + 0) * LDSTR + m] = v.x;
        qs[(4*kgp + 1) * LDSTR + m] = v.y;
        qs[(4*kgp + 2) * LDSTR + m] = v.z;
        qs[(4*kgp + 3) * LDSTR + m] = v.w;
        v = kg[idx];
        ks[(4*kgp + 0) * LDSTR + m] = v.x;
        ks[(4*kgp + 1) * LDSTR + m] = v.y;
        ks[(4*kgp + 2) * LDSTR + m] = v.z;
        ks[(4*kgp + 3) * LDSTR + m] = v.w;
    }
    for (int idx = t; idx < 16 * 64; idx += 256) {
        const int o = idx >> 6, c = idx & 63;
        bA[o][c] = bias[(size_t)(b * 32 + 2*o)     * 1024 + n0 + c];
        bB[o][c] = bias[(size_t)(b * 32 + 2*o + 1) * 1024 + m0 + c];
    }
    if (t < 64) padv[t] = mask[b * 1024 + n0 + t];
    __syncthreads();

    const int tn = t & 15, tm = t >> 4;
    float acc[4][4];
    #pragma unroll
    for (int i = 0; i < 4; ++i)
        #pragma unroll
        for (int c = 0; c < 4; ++c) acc[i][c] = 0.f;

    #pragma unroll 8
    for (int k = 0; k < 64; ++k) {
        const float4 qv = *(const float4*)&qs[k * LDSTR + 4 * tm];
        const float4 kv = *(const float4*)&ks[k * LDSTR + 4 * tn];
        const float qa[4] = {qv.x, qv.y, qv.z, qv.w};
        const float ka[4] = {kv.x, kv.y, kv.z, kv.w};
        #pragma unroll
        for (int i = 0; i < 4; ++i)
            #pragma unroll
            for (int c = 0; c < 4; ++c)
                acc[i][c] = fmaf(qa[i], ka[c], acc[i][c]);
    }

    // ---- Epilogue: 16 output planes, nontemporal float4 stores (bypass L2 allocation) ----
    // out = (acc/8 + a + vb)*p - (1-p)*NEG - causal*NEG
    //     = fma(vb, p[c], a[c]*p[c] + S[i][c]),  S[i][c] = acc*0.125*p[c] - (1-p)NEG - causalNEG
    const float4 pv = *(const float4*)&padv[4 * tn];
    const float p[4] = {pv.x, pv.y, pv.z, pv.w};
    const int ng = n0 + 4 * tn;

    float S[4][4];
    #pragma unroll
    for (int i = 0; i < 4; ++i) {
        const int mg = m0 + 4 * tm + i;
        #pragma unroll
        for (int c = 0; c < 4; ++c) {
            float kadd = (p[c] - 1.f) * NEGV;          // -(1-p)*NEG
            if (ng + c < mg) kadd -= NEGV;             // tril(-1) causal
            S[i][c] = fmaf(acc[i][c] * 0.125f, p[c], kadd);
        }
    }

    #pragma unroll
    for (int o = 0; o < 16; ++o) {
        const float4 av = *(const float4*)&bA[o][4 * tn];
        const float ap[4] = {av.x * p[0], av.y * p[1], av.z * p[2], av.w * p[3]};
        float* outp = out + ((size_t)((b * 16 + o) * 1024 + m0 + 4 * tm)) * 1024 + ng;
        #pragma unroll
        for (int i = 0; i < 4; ++i) {
            const float vb = bB[o][4 * tm + i];
            nt_float4 r4;
            r4.x = fmaf(vb, p[0], ap[0] + S[i][0]);
            r4.y = fmaf(vb, p[1], ap[1] + S[i][1]);
            r4.z = fmaf(vb, p[2], ap[2] + S[i][2]);
            r4.w = fmaf(vb, p[3], ap[3] + S[i][3]);
            __builtin_nontemporal_store(r4, (nt_float4*)(outp + (size_t)i * 1024));
        }
    }
}

extern "C" void kernel_launch(void* const* d_in, const int* in_sizes, int n_in,
                              void* d_out, int out_size, void* d_ws, size_t ws_size,
                              hipStream_t stream) {
    const float* x    = (const float*)d_in[0];
    const float* mask = (const float*)d_in[1];
    const float* W1   = (const float*)d_in[2];
    const float* b1   = (const float*)d_in[3];
    const float* W2   = (const float*)d_in[4];
    const float* b2   = (const float*)d_in[5];
    float* out = (float*)d_out;

    float* ws   = (float*)d_ws;
    float* qw   = ws;                       // 4096*64 floats
    float* kw   = ws + 4096 * 64;           // 4096*64 floats
    float* bias = ws + 2 * 4096 * 64;       // 4*32*1024 floats  (total ~2.6 MB)

    hipLaunchKernelGGL(k1_fused, dim3(256), dim3(256), 0, stream,
                       x, W1, b1, W2, b2, qw, kw, bias);
    hipLaunchKernelGGL(k2_outer, dim3(16, 16, 4), dim3(256), 0, stream,
                       qw, kw, bias, mask, out);
}

// Round 4
// 358.973 us; speedup vs baseline: 1.1626x; 1.1626x over previous
//
#include <hip/hip_runtime.h>
#include <math.h>

#define NEGV 1000000000000.0f
#define LDSTR 68   // 64 + 4 pad: keeps 16B alignment for float4 LDS reads, breaks bank conflicts

// ---------------- Kernel 1: h = x@W1+b1; RoPE -> qw,kw; bias = (h@W2+b2)/2 ----------------
// grid 256 blocks x 256 threads; each block handles 16 rows of the 4096 (b*s) rows.
// v2: x tile staged in LDS via coalesced float4 loads (v1 used 4B scalar K$ loads at
// 1 wave/SIMD -> exposed miss latency, theory: ~150us).
__global__ __launch_bounds__(256) void k1_fused(
    const float* __restrict__ x,    // (4096, 768)
    const float* __restrict__ W1,   // (768, 128)
    const float* __restrict__ b1,   // (128)
    const float* __restrict__ W2,   // (128, 32)
    const float* __restrict__ b2,   // (32)
    float* __restrict__ qw,         // (4096, 64)
    float* __restrict__ kw,         // (4096, 64)
    float* __restrict__ bias)       // (4, 32, 1024)
{
    __shared__ float xs[16][772];   // 16 rows x 768, +4 pad (4-bank row shift, b128-aligned)
    __shared__ float hs[16][132];
    const int t    = threadIdx.x;
    const int row0 = blockIdx.x * 16;

    // ---- stage x tile (16 x 768 = 48 KB) into LDS, float4 coalesced, 12 loads/thread ----
    {
        const float4* xg = (const float4*)(x + (size_t)row0 * 768);
        #pragma unroll
        for (int it = 0; it < 12; ++it) {
            const int idx = t + it * 256;            // 0..3071
            const int r = idx / 192, c4 = idx - r * 192;
            const float4 v = xg[idx];
            *(float4*)&xs[r][c4 * 4] = v;
        }
    }
    __syncthreads();

    // ---- GEMM: thread = 2 rows x 4 cols. x from LDS (broadcast b128), W1 float4 VMEM ----
    const int jc = (t & 31) * 4;       // col group (4 consecutive cols of 128)
    const int rg = (t >> 5) * 2;       // row pair (0,2,4,..,14)
    float accA[4] = {0.f,0.f,0.f,0.f};
    float accB[4] = {0.f,0.f,0.f,0.f};
    #pragma unroll 2
    for (int k = 0; k < 768; k += 4) {
        const float4 xa = *(const float4*)&xs[rg][k];
        const float4 xb = *(const float4*)&xs[rg + 1][k];
        const float xav[4] = {xa.x, xa.y, xa.z, xa.w};
        const float xbv[4] = {xb.x, xb.y, xb.z, xb.w};
        #pragma unroll
        for (int kk = 0; kk < 4; ++kk) {
            const float4 w = *(const float4*)&W1[(size_t)(k + kk) * 128 + jc];
            const float wv[4] = {w.x, w.y, w.z, w.w};
            #pragma unroll
            for (int c = 0; c < 4; ++c) {
                accA[c] = fmaf(xav[kk], wv[c], accA[c]);
                accB[c] = fmaf(xbv[kk], wv[c], accB[c]);
            }
        }
    }
    {
        const float4 bv = *(const float4*)&b1[jc];
        const float bvv[4] = {bv.x, bv.y, bv.z, bv.w};
        #pragma unroll
        for (int c = 0; c < 4; ++c) {
            hs[rg][jc + c]     = accA[c] + bvv[c];
            hs[rg + 1][jc + c] = accB[c] + bvv[c];
        }
    }
    __syncthreads();

    // ---- RoPE. qw[c]=h[2c], kw[c]=h[2c+1] ----
    for (int idx = t; idx < 16 * 64; idx += 256) {
        const int r = idx >> 6, c = idx & 63;
        const int rowg = row0 + r;
        const int s = rowg & 1023;
        const int f = c & 31;
        const float invf = exp2f(-0.4152410118609203f * (float)f); // 10000^(-f/32)
        const float ang = (float)s * invf;
        float sn, cs;
        sincosf(ang, &sn, &cs);
        const int   pc  = (c & 1) ? (c - 1) : (c + 1);
        const float sgn = (c & 1) ? sn : -sn;
        const float qv = fmaf(hs[r][2*c],     cs, hs[r][2*pc]     * sgn);
        const float kv = fmaf(hs[r][2*c + 1], cs, hs[r][2*pc + 1] * sgn);
        qw[(size_t)rowg * 64 + c] = qv;
        kw[(size_t)rowg * 64 + c] = kv;
    }

    // ---- bias[b][c][s] = (h[row] . W2[:,c] + b2[c]) * 0.5 ----
    for (int idx = t; idx < 16 * 32; idx += 256) {
        const int r = idx >> 5, c = idx & 31;
        const int rowg = row0 + r;
        const int s = rowg & 1023, bb = rowg >> 10;
        float a = 0.f;
        #pragma unroll 4
        for (int k = 0; k < 128; ++k)
            a = fmaf(hs[r][k], W2[k * 32 + c], a);
        bias[(size_t)(bb * 32 + c) * 1024 + s] = (a + b2[c]) * 0.5f;
    }
}

// ---------------- Kernel 2: out[b,o,m,n] = qk/8 + bA[o][n] + bB[o][m], mask + causal ------
// grid (16,16,4) = (nTile, mTile, b); 256 threads; 64x64 (m,n) tile; 4x4 per thread.
// (reverted exactly to the R1 version: regular float4 stores, original epilogue)
__global__ __launch_bounds__(256) void k2_outer(
    const float* __restrict__ qw, const float* __restrict__ kw,
    const float* __restrict__ bias, const float* __restrict__ mask,
    float* __restrict__ out)
{
    __shared__ float qs[64 * LDSTR];   // [k][m]
    __shared__ float ks[64 * LDSTR];   // [k][n]
    __shared__ float bA[16][64];       // bias[b][2o][n-tile]
    __shared__ float bB[16][64];       // bias[b][2o+1][m-tile]
    __shared__ float padv[64];

    const int t  = threadIdx.x;
    const int n0 = blockIdx.x * 64;
    const int m0 = blockIdx.y * 64;
    const int b  = blockIdx.z;

    const float4* qg = (const float4*)(qw + (size_t)(b * 1024 + m0) * 64);
    const float4* kg = (const float4*)(kw + (size_t)(b * 1024 + n0) * 64);
    #pragma unroll
    for (int it = 0; it < 4; ++it) {
        const int idx = t + it * 256;          // 0..1023 ; = m*16 + kgp
        const int m = idx >> 4, kgp = idx & 15;
        float4 v = qg[idx];
        qs[(4*kgp + 0) * LDSTR + m] = v.x;
        qs[(4*kgp + 1) * LDSTR + m] = v.y;
        qs[(4*kgp + 2) * LDSTR + m] = v.z;
        qs[(4*kgp + 3) * LDSTR + m] = v.w;
        v = kg[idx];
        ks[(4*kgp + 0) * LDSTR + m] = v.x;
        ks[(4*kgp + 1) * LDSTR + m] = v.y;
        ks[(4*kgp + 2) * LDSTR + m] = v.z;
        ks[(4*kgp + 3) * LDSTR + m] = v.w;
    }
    for (int idx = t; idx < 16 * 64; idx += 256) {
        const int o = idx >> 6, c = idx & 63;
        bA[o][c] = bias[(size_t)(b * 32 + 2*o)     * 1024 + n0 + c];
        bB[o][c] = bias[(size_t)(b * 32 + 2*o + 1) * 1024 + m0 + c];
    }
    if (t < 64) padv[t] = mask[b * 1024 + n0 + t];
    __syncthreads();

    const int tn = t & 15, tm = t >> 4;
    float acc[4][4];
    #pragma unroll
    for (int i = 0; i < 4; ++i)
        #pragma unroll
        for (int c = 0; c < 4; ++c) acc[i][c] = 0.f;

    #pragma unroll 8
    for (int k = 0; k < 64; ++k) {
        const float4 qv = *(const float4*)&qs[k * LDSTR + 4 * tm];
        const float4 kv = *(const float4*)&ks[k * LDSTR + 4 * tn];
        const float qa[4] = {qv.x, qv.y, qv.z, qv.w};
        const float ka[4] = {kv.x, kv.y, kv.z, kv.w};
        #pragma unroll
        for (int i = 0; i < 4; ++i)
            #pragma unroll
            for (int c = 0; c < 4; ++c)
                acc[i][c] = fmaf(qa[i], ka[c], acc[i][c]);
    }

    const float4 pv = *(const float4*)&padv[4 * tn];
    const float p[4] = {pv.x, pv.y, pv.z, pv.w};
    float negterm[4];
    #pragma unroll
    for (int c = 0; c < 4; ++c) negterm[c] = (1.f - p[c]) * NEGV;
    const int ng = n0 + 4 * tn;

    #pragma unroll
    for (int o = 0; o < 16; ++o) {
        const float4 av = *(const float4*)&bA[o][4 * tn];
        const float a[4] = {av.x, av.y, av.z, av.w};
        #pragma unroll
        for (int i = 0; i < 4; ++i) {
            const int mg = m0 + 4 * tm + i;
            const float vb = bB[o][4 * tm + i];
            float rv[4];
            #pragma unroll
            for (int c = 0; c < 4; ++c) {
                float v = fmaf(acc[i][c], 0.125f, a[c] + vb);
                v = v * p[c] - negterm[c];
                if (ng + c < mg) v -= NEGV;   // tril(-1) causal mask
                rv[c] = v;
            }
            float4 r4; r4.x = rv[0]; r4.y = rv[1]; r4.z = rv[2]; r4.w = rv[3];
            *(float4*)(out + ((size_t)((b * 16 + o) * 1024 + mg)) * 1024 + ng) = r4;
        }
    }
}

extern "C" void kernel_launch(void* const* d_in, const int* in_sizes, int n_in,
                              void* d_out, int out_size, void* d_ws, size_t ws_size,
                              hipStream_t stream) {
    const float* x    = (const float*)d_in[0];
    const float* mask = (const float*)d_in[1];
    const float* W1   = (const float*)d_in[2];
    const float* b1   = (const float*)d_in[3];
    const float* W2   = (const float*)d_in[4];
    const float* b2   = (const float*)d_in[5];
    float* out = (float*)d_out;

    float* ws   = (float*)d_ws;
    float* qw   = ws;                       // 4096*64 floats
    float* kw   = ws + 4096 * 64;           // 4096*64 floats
    float* bias = ws + 2 * 4096 * 64;       // 4*32*1024 floats  (total ~2.6 MB)

    hipLaunchKernelGGL(k1_fused, dim3(256), dim3(256), 0, stream,
                       x, W1, b1, W2, b2, qw, kw, bias);
    hipLaunchKernelGGL(k2_outer, dim3(16, 16, 4), dim3(256), 0, stream,
                       qw, kw, bias, mask, out);
}